// Round 16
// baseline (267.310 us; speedup 1.0000x reference)
//
#include <hip/hip_runtime.h>
#include <hip/hip_bf16.h>
#include <cstdint>
#include <cstddef>

// Problem constants
#define B_   2
#define S_   2048
#define H_   1024
#define NH   16
#define DH   64
#define LOG2E 1.4426950408889634f
#define SCALE2 (0.125f * LOG2E)   // D^-0.5 * log2(e): softmax done in exp2 domain

typedef __hip_bfloat16 bf16;
typedef short bf16x8 __attribute__((ext_vector_type(8)));   // 8 bf16 in 4 VGPRs
typedef float f32x4 __attribute__((ext_vector_type(4)));

#define MFMA16(a, b, c) __builtin_amdgcn_mfma_f32_16x16x32_bf16((a), (b), (c), 0, 0, 0)

__device__ __forceinline__ void async16(const void* g, void* l) {
  __builtin_amdgcn_global_load_lds(
      (const __attribute__((address_space(1))) void*)g,
      (__attribute__((address_space(3))) void*)l,
      16, 0, 0);
}

// ---------------------------------------------------------------------------
// Fused prep kernel (one dispatch, grid 8208):
//  blocks [0,4096):     convert x f32->bf16; i=(L*256+tid)*4 (R5-proven)
//  blocks [4096,7168):  transpose+convert qkv [1024][3072] -> [3072][1024]
//  blocks [7168,8192):  transpose+convert out_w [1024][1024] -> [1024][1024]
//  blocks [8192,8208):  rpe cumsum * LOG2E (exp2-domain bias)
// ---------------------------------------------------------------------------
__device__ __forceinline__ void tr_body(const float* __restrict__ src,
                                        bf16* __restrict__ dst, int R, int C,
                                        int c0, int r0, bf16 (*tile)[33], int tid) {
  int tx = tid & 31, ty = tid >> 5;   // 32 x 8
  for (int i = 0; i < 32; i += 8)
    tile[ty + i][tx] = __float2bfloat16(src[(size_t)(r0 + ty + i) * C + c0 + tx]);
  __syncthreads();
  for (int i = 0; i < 32; i += 8)
    dst[(size_t)(c0 + ty + i) * R + r0 + tx] = tile[tx][ty + i];
}

__global__ __launch_bounds__(256)
void prep(const float* __restrict__ x, bf16* __restrict__ xb,
          const float* __restrict__ qkv, bf16* __restrict__ qkvT,
          const float* __restrict__ outw, bf16* __restrict__ outwT,
          const float* __restrict__ rpe, float* __restrict__ cum) {
  __shared__ char pm[2176] __attribute__((aligned(16)));
  const int L = blockIdx.x, tid = threadIdx.x;
  if (L < 4096) {
    int i = (L * 256 + tid) * 4;
    float4 v = *(const float4*)(x + i);
    bf16 o[4] = {__float2bfloat16(v.x), __float2bfloat16(v.y),
                 __float2bfloat16(v.z), __float2bfloat16(v.w)};
    *(uint64_t*)(xb + i) = *(const uint64_t*)o;
  } else if (L < 7168) {
    int t = L - 4096;
    int cx = t % 96, ry = t / 96;
    tr_body(qkv, qkvT, 1024, 3072, cx * 32, ry * 32, (bf16(*)[33])pm, tid);
  } else if (L < 8192) {
    int t = L - 7168;
    int cx = t & 31, ry = t >> 5;
    tr_body(outw, outwT, 1024, 1024, cx * 32, ry * 32, (bf16(*)[33])pm, tid);
  } else {
    // rpe cumsum (scaled by LOG2E)
    float* ssum = (float*)pm;
    int n = L - 8192;
    float loc[8];
    float s = 0.f;
    int base = tid * 8;
#pragma unroll
    for (int u = 0; u < 8; ++u) {
      loc[u] = rpe[n * S_ + base + u];
      s += loc[u];
    }
    ssum[tid] = s;
    __syncthreads();
    float own = s;
    for (int off = 1; off < 256; off <<= 1) {
      float v = (tid >= off) ? ssum[tid - off] : 0.f;
      __syncthreads();
      ssum[tid] += v;
      __syncthreads();
    }
    float run = ssum[tid] - own;   // exclusive prefix of this thread's chunk
#pragma unroll
    for (int u = 0; u < 8; ++u) {
      run += loc[u];
      cum[n * S_ + base + u] = run * LOG2E;
    }
  }
}

// ---------------------------------------------------------------------------
// GEMM: C[M x Nc] = A[M x 1024] * Bt[Nc x 1024]^T, bf16 in, f32 acc.
// 256 threads (4 waves). XOR-swizzled LDS -> 2-way reads (free).
// MODE 0: 128x128 tile (NT=4). Epilogue re-layouts each wave's 64x64 tile
//   through wave-private LDS then b128 stores: q,k as [bn][s][d], V
//   TRANSPOSED as [bn][d][s]. bounds(256,3): 768 blocks = 3/CU, no tail.
// MODE 1: 128x64 tile (NT=2), grid (16,32)=512 blocks = 2/CU. f32 store.
// ---------------------------------------------------------------------------
template <int MODE>
__global__ __launch_bounds__(256, MODE == 0 ? 3 : 2)
void gemm_bt(const bf16* __restrict__ A, const bf16* __restrict__ Bt,
             bf16* __restrict__ C0, bf16* __restrict__ C1, bf16* __restrict__ C2,
             float* __restrict__ F0) {
  constexpr int NT = (MODE == 0) ? 4 : 2;     // n-subtiles per wave
  constexpr int NB = NT * 32;                 // block n-extent: 128 or 64
  __shared__ char smem[MODE == 0 ? 36864 : 12288] __attribute__((aligned(16)));
  bf16* As = (bf16*)smem;              // [128*32]
  bf16* Bs = (bf16*)(smem + 8192);     // [NB*32]
  const int tid = threadIdx.x, lane = tid & 63, w = tid >> 6;
  const int lr = lane & 15, lq = lane >> 4;
  const int m0 = blockIdx.y * 128, n0 = blockIdx.x * NB;
  const int wm = (w & 1) * 64, wn = (w >> 1) * (NT * 16);

  f32x4 acc[4][NT] = {};

  for (int k0 = 0; k0 < 1024; k0 += 32) {
    __syncthreads();
#pragma unroll
    for (int t = 0; t < 2; ++t) {
      int c = (t * 4 + w) * 64 + lane;          // 16B-chunk id 0..511
      int row = c >> 2, ch = c & 3;
      int k8 = (ch ^ ((row >> 1) & 3)) * 8;     // swizzled source chunk
      async16(A + (size_t)(m0 + row) * 1024 + k0 + k8,
              (char*)As + (size_t)(t * 4 + w) * 1024 + lane * 16);
    }
#pragma unroll
    for (int t = 0; t < NB / 64; ++t) {
      int c = (t * 4 + w) * 64 + lane;          // chunk id, NB*4 total
      int row = c >> 2, ch = c & 3;
      int k8 = (ch ^ ((row >> 1) & 3)) * 8;
      async16(Bt + (size_t)(n0 + row) * 1024 + k0 + k8,
              (char*)Bs + (size_t)(t * 4 + w) * 1024 + lane * 16);
    }
    __syncthreads();
    bf16x8 af[4], bfr[NT];
#pragma unroll
    for (int mt = 0; mt < 4; ++mt) {
      int row = wm + mt * 16 + lr;
      af[mt] = *(const bf16x8*)(As + row * 32 + ((lq ^ ((row >> 1) & 3)) << 3));
    }
#pragma unroll
    for (int nt = 0; nt < NT; ++nt) {
      int row = wn + nt * 16 + lr;
      bfr[nt] = *(const bf16x8*)(Bs + row * 32 + ((lq ^ ((row >> 1) & 3)) << 3));
    }
#pragma unroll
    for (int mt = 0; mt < 4; ++mt)
#pragma unroll
      for (int nt = 0; nt < NT; ++nt)
        acc[mt][nt] = MFMA16(af[mt], bfr[nt], acc[mt][nt]);
  }

  if (MODE == 0) {
    __syncthreads();   // all As/Bs reads done; reuse LDS for epilogue tiles
    bf16* E = (bf16*)smem + w * (64 * 72);   // wave-private [64][72]
    const int cbase = n0 + wn;               // 64-aligned
    const int mm = cbase >> 10, nn = (cbase >> 6) & 15;
    const int bb = (m0 + wm) >> 11;
    const int sbase = (m0 + wm) & 2047;
    if (mm < 2) {
      // write acc as [s][d] into E
#pragma unroll
      for (int mt = 0; mt < 4; ++mt)
#pragma unroll
        for (int nt = 0; nt < 4; ++nt)
#pragma unroll
          for (int r = 0; r < 4; ++r)
            E[(mt * 16 + lq * 4 + r) * 72 + nt * 16 + lr] =
                __float2bfloat16(acc[mt][nt][r]);
      // wave-private readback (in-wave lgkm ordering), b128 stores
      bf16* dst = (mm == 0 ? C0 : C1) +
                  ((size_t)(bb * NH + nn) * S_ + sbase) * DH;
#pragma unroll
      for (int it = 0; it < 8; ++it) {
        int c = it * 64 + lane;
        int rw = c >> 3, c8 = c & 7;
        *(uint4*)(dst + (size_t)rw * DH + c8 * 8) =
            *(const uint4*)(E + rw * 72 + c8 * 8);
      }
    } else {
      // V: write acc as [d][s] into E
#pragma unroll
      for (int mt = 0; mt < 4; ++mt)
#pragma unroll
        for (int nt = 0; nt < 4; ++nt)
#pragma unroll
          for (int r = 0; r < 4; ++r)
            E[(nt * 16 + lr) * 72 + mt * 16 + lq * 4 + r] =
                __float2bfloat16(acc[mt][nt][r]);
      bf16* dst = C2 + (size_t)(bb * NH + nn) * DH * S_;
#pragma unroll
      for (int it = 0; it < 8; ++it) {
        int c = it * 64 + lane;
        int dr = c >> 3, c8 = c & 7;
        *(uint4*)(dst + (size_t)dr * S_ + sbase + c8 * 8) =
            *(const uint4*)(E + dr * 72 + c8 * 8);
      }
    }
  } else {
#pragma unroll
    for (int mt = 0; mt < 4; ++mt)
#pragma unroll
      for (int nt = 0; nt < NT; ++nt)
#pragma unroll
        for (int r = 0; r < 4; ++r) {
          int rM = m0 + wm + mt * 16 + lq * 4 + r;
          int cN = n0 + wn + nt * 16 + lr;
          F0[(size_t)rM * 1024 + cN] = acc[mt][nt][r];
        }
  }
}

// ---------------------------------------------------------------------------
// Flash attention. R13 structure, two changes:
//  (1) bias path REVERTED to R13's b32 cumbuf gather (R15's phase-shifted
//      b128 had phase stride 192 ≡ 0 mod 32 banks -> 3x conflicts, regressed).
//  (2) K fragments read DIRECTLY FROM GLOBAL (no LDS round trip): each lane's
//      kf is a contiguous 16B of the [s][d] K row; wave pattern = dense 64B
//      segments, L2-resident (XCD-pinned). Deletes K staging + kf ds_reads,
//      halves the staging-barrier vmcnt drain, and shrinks LDS 53K->34.8K
//      -> 4 blocks/CU (fa is latency-bound: wall ~2400 cyc/iter vs ~1100
//      modeled throughput; more co-resident blocks hide it).
// No-max exp2 softmax (R13-verified), MFMA row sums.
// q,k: [bn][S][D] bf16;  vt: [bn][D][S] bf16;  cum: [N][S] f32 (xLOG2E);
// mix out: [b][s][n][d] bf16
// 1D grid 1024, block 256 (4 waves). xcd=L&7 pins 4 heads per XCD; ti
// descends with L. One 64-row Q-tile per block; nj=(ti>>1)+1 KV-tile iters.
// LDS: V [0,16384); Ps[64][136] [16384,33792); cumbuf[256] [33792,34816).
// 34816*4 = 139264 <= 160 KB -> 4 blocks/CU.
// ---------------------------------------------------------------------------
__global__ __launch_bounds__(256, 4)
void fa_kernel(const bf16* __restrict__ q, const bf16* __restrict__ k,
               const bf16* __restrict__ vt, const float* __restrict__ cum,
               bf16* __restrict__ mix) {
  __shared__ char smem[34816] __attribute__((aligned(16)));
  bf16* Ps = (bf16*)(smem + 16384);             // [64][136]
  float* cumbuf = (float*)(smem + 33792);       // [256]

  const int tid = threadIdx.x, lane = tid & 63, w = tid >> 6;  // w: 0..3
  const int lr = lane & 15, lq = lane >> 4;

  const int L = blockIdx.x;
  const int xcd = L & 7, slot = L >> 3;
  const int bn = xcd + 8 * (slot >> 5);         // 4 heads per XCD
  const int ti = 31 - (slot & 31);              // descending work
  const int n = bn & (NH - 1);
  const int b = bn >> 4;
  const float* cumn = cum + n * S_;

  const int i0 = ti * 64;
  const int nj = (ti >> 1) + 1;                 // KV tiles (128 cols each)

  // Q fragments (B-operand for S^T = K*Q^T): lane n=lr reads Q row lr
  const bf16* qbase = q + ((size_t)bn * S_ + i0 + w * 16) * DH;
  bf16x8 qf[2];
#pragma unroll
  for (int kt = 0; kt < 2; ++kt)
    qf[kt] = *(const bf16x8*)(qbase + lr * DH + kt * 32 + lq * 8);

  // all-ones B fragment for the l row-sum MFMA
  bf16x8 ones;
#pragma unroll
  for (int u = 0; u < 8; ++u) ones[u] = (short)0x3F80;

  f32x4 oacc[4] = {};
  f32x4 lacc = {};                              // row sums, C-layout rows lq*4+r
  const int iloc = w * 16 + lr;
  const bf16* kbase = k + (size_t)bn * S_ * DH;

  for (int jt = 0; jt < nj; ++jt) {
    const int j0 = jt * 128;
    const bool diag = (jt == nj - 1);
    __syncthreads();   // prior V/P/cum reads done; regions free

    // stage Vt tile (swizzled: slot (row,c) holds global chunk c^(row&15))
    const char* vsrc = (const char*)(vt + (size_t)bn * DH * S_);
#pragma unroll
    for (int t = 0; t < 4; ++t) {
      int cb = t * 4 + w;
      int row = cb * 4 + (lane >> 4);          // d index 0..63
      int cs = (lane & 15) ^ (row & 15);
      async16(vsrc + (size_t)row * (S_ * 2) + j0 * 2 + cs * 16,
              smem + cb * 1024 + lane * 16);
    }
    // stage cum window: cumbuf[t] = cumn[clamp(i0-j0-127+t)]
    {
      int src = i0 - j0 - 127 + tid;
      src = src < 0 ? 0 : (src > S_ - 1 ? S_ - 1 : src);
      cumbuf[tid] = cumn[src];
    }
    __syncthreads();   // staging complete

    // S^T = K * Q^T with K fragments straight from global (L2-resident):
    // sa[nt][r] = S[i=i0+iloc][j = j0 + nt*16 + lq*4 + r]
    const bf16* ksrc = kbase + (size_t)j0 * DH;
    f32x4 sa[8] = {};
#pragma unroll
    for (int kt = 0; kt < 2; ++kt)
#pragma unroll
      for (int nt = 0; nt < 8; ++nt) {
        bf16x8 kf = *(const bf16x8*)(ksrc + (nt * 16 + lr) * DH + kt * 32 + lq * 8);
        sa[nt] = MFMA16(kf, qf[kt], sa[nt]);
      }

    // p = exp2(s*SCALE2 + cum[i-j]) (no max subtraction), pack, write P
    const int doff = i0 - j0;     // 0 or 64 on diagonal tile
    if (!diag) {
#pragma unroll
      for (int nt = 0; nt < 8; ++nt) {
        bf16 pk[4];
#pragma unroll
        for (int r = 0; r < 4; ++r) {
          int rel = iloc - nt * 16 - lq * 4 - r;
          float p = exp2f(sa[nt][r] * SCALE2 + cumbuf[127 + rel]);
          pk[r] = __float2bfloat16(p);
        }
        *(uint64_t*)(Ps + iloc * 136 + nt * 16 + lq * 4) = *(const uint64_t*)pk;
      }
    } else {
#pragma unroll
      for (int nt = 0; nt < 8; ++nt) {
        bf16 pk[4];
#pragma unroll
        for (int r = 0; r < 4; ++r) {
          int rel = iloc - nt * 16 - lq * 4 - r;
          float p = (doff + rel >= 0)
                        ? exp2f(sa[nt][r] * SCALE2 + cumbuf[127 + rel])
                        : 0.f;
          pk[r] = __float2bfloat16(p);
        }
        *(uint64_t*)(Ps + iloc * 136 + nt * 16 + lq * 4) = *(const uint64_t*)pk;
      }
    }

    // O += P V; l += P 1  (wave-private P rows; in-wave DS ordering suffices)
#pragma unroll
    for (int kt2 = 0; kt2 < 4; ++kt2) {
      bf16x8 pf = *(const bf16x8*)(Ps + (w * 16 + lr) * 136 + kt2 * 32 + lq * 8);
      lacc = MFMA16(pf, ones, lacc);
#pragma unroll
      for (int dt = 0; dt < 4; ++dt) {
        int vrow = dt * 16 + lr;
        bf16x8 vf = *(const bf16x8*)(smem + vrow * 256 +
                        (((kt2 * 4 + lq) ^ (vrow & 15)) << 4));
        oacc[dt] = MFMA16(pf, vf, oacc[dt]);
      }
    }
  }

  // epilogue: mix[b][s][n][d]; lacc[r] is the row sum for row lq*4+r
#pragma unroll
  for (int dt = 0; dt < 4; ++dt)
#pragma unroll
    for (int r = 0; r < 4; ++r) {
      int i = i0 + w * 16 + lq * 4 + r;
      int d = dt * 16 + lr;
      mix[((size_t)(b * S_ + i) * NH + n) * DH + d] =
          __float2bfloat16(oacc[dt][r] / lacc[r]);
    }
}

// ---------------------------------------------------------------------------
extern "C" void kernel_launch(void* const* d_in, const int* in_sizes, int n_in,
                              void* d_out, int out_size, void* d_ws, size_t ws_size,
                              hipStream_t stream) {
  const float* x     = (const float*)d_in[0];   // [B,S,H] f32
  const float* qkv   = (const float*)d_in[1];   // [H,3,N,D] f32 == [1024][3072]
  const float* out_w = (const float*)d_in[2];   // [N,D,H] f32   == [1024][1024]
  const float* rpe   = (const float*)d_in[3];   // [N,S] f32
  float* out = (float*)d_out;                   // [B,S,H] f32

  char* ws = (char*)d_ws;
  bf16* qkvT  = (bf16*)(ws + 0);          // [3072][1024] bf16   6291456 B
  bf16* outwT = (bf16*)(ws + 6291456);    // [1024][1024] bf16   2097152 B
  bf16* xb    = (bf16*)(ws + 8388608);    // [4096][1024] bf16   8388608 B
  bf16* qb    = (bf16*)(ws + 16777216);   // [bn][S][D]          8388608 B
  bf16* kb    = (bf16*)(ws + 25165824);   // [bn][S][D]          8388608 B
  bf16* vtb   = (bf16*)(ws + 33554432);   // [bn][D][S]          8388608 B
  bf16* mixb  = (bf16*)(ws + 41943040);   // [b][s][n][d]        8388608 B
  float* cum  = (float*)(ws + 50331648);  // [N][S] f32 (xLOG2E)  131072 B

  // 1. fused prep: convert x, transpose+convert weights, rpe cumsum
  prep<<<8208, 256, 0, stream>>>(x, xb, qkv, qkvT, out_w, outwT, rpe, cum);
  // 2. QKV projection (V written pre-transposed; 768 blocks = 3/CU, no tail)
  gemm_bt<0><<<dim3(3072 / 128, 4096 / 128), 256, 0, stream>>>(xb, qkvT, qb, kb, vtb, nullptr);
  // 3. attention (K-direct-from-global, 4 blocks/CU, b32 bias gather)
  fa_kernel<<<1024, 256, 0, stream>>>(qb, kb, vtb, cum, mixb);
  // 4. output projection (f32 out; 128x64 tiles -> 512 blocks = 2/CU)
  gemm_bt<1><<<dim3(1024 / 64, 4096 / 128), 256, 0, stream>>>(mixb, outwT, nullptr, nullptr, nullptr, out);
}

// Round 17
// 194.663 us; speedup vs baseline: 1.3732x; 1.3732x over previous
//
#include <hip/hip_runtime.h>
#include <hip/hip_bf16.h>
#include <cstdint>
#include <cstddef>

// Problem constants
#define B_   2
#define S_   2048
#define H_   1024
#define NH   16
#define DH   64
#define LOG2E 1.4426950408889634f
#define SCALE2 (0.125f * LOG2E)   // D^-0.5 * log2(e): softmax done in exp2 domain

typedef __hip_bfloat16 bf16;
typedef short bf16x8 __attribute__((ext_vector_type(8)));   // 8 bf16 in 4 VGPRs
typedef float f32x4 __attribute__((ext_vector_type(4)));

#define MFMA16(a, b, c) __builtin_amdgcn_mfma_f32_16x16x32_bf16((a), (b), (c), 0, 0, 0)

__device__ __forceinline__ void async16(const void* g, void* l) {
  __builtin_amdgcn_global_load_lds(
      (const __attribute__((address_space(1))) void*)g,
      (__attribute__((address_space(3))) void*)l,
      16, 0, 0);
}

// ---------------------------------------------------------------------------
// Fused prep kernel (one dispatch, grid 8208):
//  blocks [0,4096):     convert x f32->bf16; i=(L*256+tid)*4 (R5-proven)
//  blocks [4096,7168):  transpose+convert qkv [1024][3072] -> [3072][1024]
//  blocks [7168,8192):  transpose+convert out_w [1024][1024] -> [1024][1024]
//  blocks [8192,8208):  rpe cumsum * LOG2E (exp2-domain bias)
// ---------------------------------------------------------------------------
__device__ __forceinline__ void tr_body(const float* __restrict__ src,
                                        bf16* __restrict__ dst, int R, int C,
                                        int c0, int r0, bf16 (*tile)[33], int tid) {
  int tx = tid & 31, ty = tid >> 5;   // 32 x 8
  for (int i = 0; i < 32; i += 8)
    tile[ty + i][tx] = __float2bfloat16(src[(size_t)(r0 + ty + i) * C + c0 + tx]);
  __syncthreads();
  for (int i = 0; i < 32; i += 8)
    dst[(size_t)(c0 + ty + i) * R + r0 + tx] = tile[tx][ty + i];
}

__global__ __launch_bounds__(256)
void prep(const float* __restrict__ x, bf16* __restrict__ xb,
          const float* __restrict__ qkv, bf16* __restrict__ qkvT,
          const float* __restrict__ outw, bf16* __restrict__ outwT,
          const float* __restrict__ rpe, float* __restrict__ cum) {
  __shared__ char pm[2176] __attribute__((aligned(16)));
  const int L = blockIdx.x, tid = threadIdx.x;
  if (L < 4096) {
    int i = (L * 256 + tid) * 4;
    float4 v = *(const float4*)(x + i);
    bf16 o[4] = {__float2bfloat16(v.x), __float2bfloat16(v.y),
                 __float2bfloat16(v.z), __float2bfloat16(v.w)};
    *(uint64_t*)(xb + i) = *(const uint64_t*)o;
  } else if (L < 7168) {
    int t = L - 4096;
    int cx = t % 96, ry = t / 96;
    tr_body(qkv, qkvT, 1024, 3072, cx * 32, ry * 32, (bf16(*)[33])pm, tid);
  } else if (L < 8192) {
    int t = L - 7168;
    int cx = t & 31, ry = t >> 5;
    tr_body(outw, outwT, 1024, 1024, cx * 32, ry * 32, (bf16(*)[33])pm, tid);
  } else {
    // rpe cumsum (scaled by LOG2E)
    float* ssum = (float*)pm;
    int n = L - 8192;
    float loc[8];
    float s = 0.f;
    int base = tid * 8;
#pragma unroll
    for (int u = 0; u < 8; ++u) {
      loc[u] = rpe[n * S_ + base + u];
      s += loc[u];
    }
    ssum[tid] = s;
    __syncthreads();
    float own = s;
    for (int off = 1; off < 256; off <<= 1) {
      float v = (tid >= off) ? ssum[tid - off] : 0.f;
      __syncthreads();
      ssum[tid] += v;
      __syncthreads();
    }
    float run = ssum[tid] - own;   // exclusive prefix of this thread's chunk
#pragma unroll
    for (int u = 0; u < 8; ++u) {
      run += loc[u];
      cum[n * S_ + base + u] = run * LOG2E;
    }
  }
}

// ---------------------------------------------------------------------------
// GEMM: C[M x Nc] = A[M x 1024] * Bt[Nc x 1024]^T, bf16 in, f32 acc.
// 256 threads (4 waves). XOR-swizzled LDS -> 2-way reads (free).
// MODE 0: 128x128 tile (NT=4). Epilogue re-layouts each wave's 64x64 tile
//   through wave-private LDS then b128 stores: q,k as [bn][s][d], V
//   TRANSPOSED as [bn][d][s]. bounds(256,3): 768 blocks = 3/CU, no tail.
// MODE 1: 128x64 tile (NT=2), grid (16,32)=512 blocks = 2/CU. f32 store.
// ---------------------------------------------------------------------------
template <int MODE>
__global__ __launch_bounds__(256, MODE == 0 ? 3 : 2)
void gemm_bt(const bf16* __restrict__ A, const bf16* __restrict__ Bt,
             bf16* __restrict__ C0, bf16* __restrict__ C1, bf16* __restrict__ C2,
             float* __restrict__ F0) {
  constexpr int NT = (MODE == 0) ? 4 : 2;     // n-subtiles per wave
  constexpr int NB = NT * 32;                 // block n-extent: 128 or 64
  __shared__ char smem[MODE == 0 ? 36864 : 12288] __attribute__((aligned(16)));
  bf16* As = (bf16*)smem;              // [128*32]
  bf16* Bs = (bf16*)(smem + 8192);     // [NB*32]
  const int tid = threadIdx.x, lane = tid & 63, w = tid >> 6;
  const int lr = lane & 15, lq = lane >> 4;
  const int m0 = blockIdx.y * 128, n0 = blockIdx.x * NB;
  const int wm = (w & 1) * 64, wn = (w >> 1) * (NT * 16);

  f32x4 acc[4][NT] = {};

  for (int k0 = 0; k0 < 1024; k0 += 32) {
    __syncthreads();
#pragma unroll
    for (int t = 0; t < 2; ++t) {
      int c = (t * 4 + w) * 64 + lane;          // 16B-chunk id 0..511
      int row = c >> 2, ch = c & 3;
      int k8 = (ch ^ ((row >> 1) & 3)) * 8;     // swizzled source chunk
      async16(A + (size_t)(m0 + row) * 1024 + k0 + k8,
              (char*)As + (size_t)(t * 4 + w) * 1024 + lane * 16);
    }
#pragma unroll
    for (int t = 0; t < NB / 64; ++t) {
      int c = (t * 4 + w) * 64 + lane;          // chunk id, NB*4 total
      int row = c >> 2, ch = c & 3;
      int k8 = (ch ^ ((row >> 1) & 3)) * 8;
      async16(Bt + (size_t)(n0 + row) * 1024 + k0 + k8,
              (char*)Bs + (size_t)(t * 4 + w) * 1024 + lane * 16);
    }
    __syncthreads();
    bf16x8 af[4], bfr[NT];
#pragma unroll
    for (int mt = 0; mt < 4; ++mt) {
      int row = wm + mt * 16 + lr;
      af[mt] = *(const bf16x8*)(As + row * 32 + ((lq ^ ((row >> 1) & 3)) << 3));
    }
#pragma unroll
    for (int nt = 0; nt < NT; ++nt) {
      int row = wn + nt * 16 + lr;
      bfr[nt] = *(const bf16x8*)(Bs + row * 32 + ((lq ^ ((row >> 1) & 3)) << 3));
    }
#pragma unroll
    for (int mt = 0; mt < 4; ++mt)
#pragma unroll
      for (int nt = 0; nt < NT; ++nt)
        acc[mt][nt] = MFMA16(af[mt], bfr[nt], acc[mt][nt]);
  }

  if (MODE == 0) {
    __syncthreads();   // all As/Bs reads done; reuse LDS for epilogue tiles
    bf16* E = (bf16*)smem + w * (64 * 72);   // wave-private [64][72]
    const int cbase = n0 + wn;               // 64-aligned
    const int mm = cbase >> 10, nn = (cbase >> 6) & 15;
    const int bb = (m0 + wm) >> 11;
    const int sbase = (m0 + wm) & 2047;
    if (mm < 2) {
      // write acc as [s][d] into E
#pragma unroll
      for (int mt = 0; mt < 4; ++mt)
#pragma unroll
        for (int nt = 0; nt < 4; ++nt)
#pragma unroll
          for (int r = 0; r < 4; ++r)
            E[(mt * 16 + lq * 4 + r) * 72 + nt * 16 + lr] =
                __float2bfloat16(acc[mt][nt][r]);
      // wave-private readback (in-wave lgkm ordering), b128 stores
      bf16* dst = (mm == 0 ? C0 : C1) +
                  ((size_t)(bb * NH + nn) * S_ + sbase) * DH;
#pragma unroll
      for (int it = 0; it < 8; ++it) {
        int c = it * 64 + lane;
        int rw = c >> 3, c8 = c & 7;
        *(uint4*)(dst + (size_t)rw * DH + c8 * 8) =
            *(const uint4*)(E + rw * 72 + c8 * 8);
      }
    } else {
      // V: write acc as [d][s] into E
#pragma unroll
      for (int mt = 0; mt < 4; ++mt)
#pragma unroll
        for (int nt = 0; nt < 4; ++nt)
#pragma unroll
          for (int r = 0; r < 4; ++r)
            E[(nt * 16 + lr) * 72 + mt * 16 + lq * 4 + r] =
                __float2bfloat16(acc[mt][nt][r]);
      bf16* dst = C2 + (size_t)(bb * NH + nn) * DH * S_;
#pragma unroll
      for (int it = 0; it < 8; ++it) {
        int c = it * 64 + lane;
        int dr = c >> 3, c8 = c & 7;
        *(uint4*)(dst + (size_t)dr * S_ + sbase + c8 * 8) =
            *(const uint4*)(E + dr * 72 + c8 * 8);
      }
    }
  } else {
#pragma unroll
    for (int mt = 0; mt < 4; ++mt)
#pragma unroll
      for (int nt = 0; nt < NT; ++nt)
#pragma unroll
        for (int r = 0; r < 4; ++r) {
          int rM = m0 + wm + mt * 16 + lq * 4 + r;
          int cN = n0 + wn + nt * 16 + lr;
          F0[(size_t)rM * 1024 + cN] = acc[mt][nt][r];
        }
  }
}

// ---------------------------------------------------------------------------
// Flash attention — EXACT R13 structure (the best measured fa: 66.2 us).
// R14 (32x32 tiles), R15 (b128 bias), R16 (K-direct-from-global) all
// regressed; K must be staged via global_load_lds (latency paid once per
// tile behind one barrier, not per-MFMA).
// No-max exp2 softmax + MFMA row-sums (R13-verified).
// q,k: [bn][S][D] bf16;  vt: [bn][D][S] bf16;  cum: [N][S] f32 (xLOG2E);
// mix out: [b][s][n][d] bf16
// 1D grid 1024, block 256 (4 waves). xcd=L&7 pins 4 heads per XCD; ti
// descends with L. One 64-row Q-tile per block; nj=(ti>>1)+1 KV-tile iters.
// S^T trick: compute S^T = K*Q^T so each lane owns ONE softmax row.
// LDS: K [0,16384); V [16384,32768); Ps[64][136] [32768,50176);
// cumbuf[256] [50176,51200). 51200*3 <= 160 KB -> 3 blocks/CU.
// ---------------------------------------------------------------------------
__global__ __launch_bounds__(256, 3)
void fa_kernel(const bf16* __restrict__ q, const bf16* __restrict__ k,
               const bf16* __restrict__ vt, const float* __restrict__ cum,
               bf16* __restrict__ mix) {
  __shared__ char smem[51200] __attribute__((aligned(16)));
  bf16* Ps = (bf16*)(smem + 32768);             // [64][136]
  float* cumbuf = (float*)(smem + 50176);       // [256]

  const int tid = threadIdx.x, lane = tid & 63, w = tid >> 6;  // w: 0..3
  const int lr = lane & 15, lq = lane >> 4;

  const int L = blockIdx.x;
  const int xcd = L & 7, slot = L >> 3;
  const int bn = xcd + 8 * (slot >> 5);         // 4 heads per XCD
  const int ti = 31 - (slot & 31);              // descending work
  const int n = bn & (NH - 1);
  const int b = bn >> 4;
  const float* cumn = cum + n * S_;

  const int i0 = ti * 64;
  const int nj = (ti >> 1) + 1;                 // KV tiles (128 cols each)

  // Q fragments (B-operand for S^T = K*Q^T): lane n=lr reads Q row lr
  const bf16* qbase = q + ((size_t)bn * S_ + i0 + w * 16) * DH;
  bf16x8 qf[2];
#pragma unroll
  for (int kt = 0; kt < 2; ++kt)
    qf[kt] = *(const bf16x8*)(qbase + lr * DH + kt * 32 + lq * 8);

  // all-ones B fragment for the l row-sum MFMA
  bf16x8 ones;
#pragma unroll
  for (int u = 0; u < 8; ++u) ones[u] = (short)0x3F80;

  f32x4 oacc[4] = {};
  f32x4 lacc = {};                              // row sums, C-layout rows lq*4+r
  const int iloc = w * 16 + lr;

  for (int jt = 0; jt < nj; ++jt) {
    const int j0 = jt * 128;
    const bool diag = (jt == nj - 1);
    __syncthreads();   // prior K/V/cum reads done; regions free

    // stage K tile (swizzled: slot (row,c) holds global chunk c^(row&7))
    const char* ksrc = (const char*)(k + ((size_t)bn * S_ + j0) * DH);
#pragma unroll
    for (int t = 0; t < 4; ++t) {
      int cb = t * 4 + w;
      int row = cb * 8 + (lane >> 3);
      int cs = (lane & 7) ^ (row & 7);
      async16(ksrc + row * 128 + cs * 16, smem + cb * 1024 + lane * 16);
    }
    // stage Vt tile (swizzled: slot (row,c) holds global chunk c^(row&15))
    const char* vsrc = (const char*)(vt + (size_t)bn * DH * S_);
#pragma unroll
    for (int t = 0; t < 4; ++t) {
      int cb = t * 4 + w;
      int row = cb * 4 + (lane >> 4);          // d index 0..63
      int cs = (lane & 15) ^ (row & 15);
      async16(vsrc + (size_t)row * (S_ * 2) + j0 * 2 + cs * 16,
              smem + 16384 + cb * 1024 + lane * 16);
    }
    // stage cum window: cumbuf[t] = cumn[clamp(i0-j0-127+t)]
    {
      int src = i0 - j0 - 127 + tid;
      src = src < 0 ? 0 : (src > S_ - 1 ? S_ - 1 : src);
      cumbuf[tid] = cumn[src];
    }
    __syncthreads();   // staging complete

    // S^T = K * Q^T: sa[nt][r] = S[i=i0+iloc][j = j0 + nt*16 + lq*4 + r]
    f32x4 sa[8] = {};
#pragma unroll
    for (int kt = 0; kt < 2; ++kt)
#pragma unroll
      for (int nt = 0; nt < 8; ++nt) {
        int krow = nt * 16 + lr;
        bf16x8 kf = *(const bf16x8*)(smem + krow * 128 +
                        (((kt * 4 + lq) ^ (krow & 7)) << 4));
        sa[nt] = MFMA16(kf, qf[kt], sa[nt]);
      }

    // p = exp2(s*SCALE2 + cum[i-j]) (no max subtraction), pack, write P
    const int doff = i0 - j0;     // 0 or 64 on diagonal tile
    if (!diag) {
#pragma unroll
      for (int nt = 0; nt < 8; ++nt) {
        bf16 pk[4];
#pragma unroll
        for (int r = 0; r < 4; ++r) {
          int rel = iloc - nt * 16 - lq * 4 - r;
          float p = exp2f(sa[nt][r] * SCALE2 + cumbuf[127 + rel]);
          pk[r] = __float2bfloat16(p);
        }
        *(uint64_t*)(Ps + iloc * 136 + nt * 16 + lq * 4) = *(const uint64_t*)pk;
      }
    } else {
#pragma unroll
      for (int nt = 0; nt < 8; ++nt) {
        bf16 pk[4];
#pragma unroll
        for (int r = 0; r < 4; ++r) {
          int rel = iloc - nt * 16 - lq * 4 - r;
          float p = (doff + rel >= 0)
                        ? exp2f(sa[nt][r] * SCALE2 + cumbuf[127 + rel])
                        : 0.f;
          pk[r] = __float2bfloat16(p);
        }
        *(uint64_t*)(Ps + iloc * 136 + nt * 16 + lq * 4) = *(const uint64_t*)pk;
      }
    }

    // O += P V; l += P 1  (wave-private P rows; in-wave DS ordering suffices)
#pragma unroll
    for (int kt2 = 0; kt2 < 4; ++kt2) {
      bf16x8 pf = *(const bf16x8*)(Ps + (w * 16 + lr) * 136 + kt2 * 32 + lq * 8);
      lacc = MFMA16(pf, ones, lacc);
#pragma unroll
      for (int dt = 0; dt < 4; ++dt) {
        int vrow = dt * 16 + lr;
        bf16x8 vf = *(const bf16x8*)(smem + 16384 + vrow * 256 +
                        (((kt2 * 4 + lq) ^ (vrow & 15)) << 4));
        oacc[dt] = MFMA16(pf, vf, oacc[dt]);
      }
    }
  }

  // epilogue: mix[b][s][n][d]; lacc[r] is the row sum for row lq*4+r
#pragma unroll
  for (int dt = 0; dt < 4; ++dt)
#pragma unroll
    for (int r = 0; r < 4; ++r) {
      int i = i0 + w * 16 + lq * 4 + r;
      int d = dt * 16 + lr;
      mix[((size_t)(b * S_ + i) * NH + n) * DH + d] =
          __float2bfloat16(oacc[dt][r] / lacc[r]);
    }
}

// ---------------------------------------------------------------------------
extern "C" void kernel_launch(void* const* d_in, const int* in_sizes, int n_in,
                              void* d_out, int out_size, void* d_ws, size_t ws_size,
                              hipStream_t stream) {
  const float* x     = (const float*)d_in[0];   // [B,S,H] f32
  const float* qkv   = (const float*)d_in[1];   // [H,3,N,D] f32 == [1024][3072]
  const float* out_w = (const float*)d_in[2];   // [N,D,H] f32   == [1024][1024]
  const float* rpe   = (const float*)d_in[3];   // [N,S] f32
  float* out = (float*)d_out;                   // [B,S,H] f32

  char* ws = (char*)d_ws;
  bf16* qkvT  = (bf16*)(ws + 0);          // [3072][1024] bf16   6291456 B
  bf16* outwT = (bf16*)(ws + 6291456);    // [1024][1024] bf16   2097152 B
  bf16* xb    = (bf16*)(ws + 8388608);    // [4096][1024] bf16   8388608 B
  bf16* qb    = (bf16*)(ws + 16777216);   // [bn][S][D]          8388608 B
  bf16* kb    = (bf16*)(ws + 25165824);   // [bn][S][D]          8388608 B
  bf16* vtb   = (bf16*)(ws + 33554432);   // [bn][D][S]          8388608 B
  bf16* mixb  = (bf16*)(ws + 41943040);   // [b][s][n][d]        8388608 B
  float* cum  = (float*)(ws + 50331648);  // [N][S] f32 (xLOG2E)  131072 B

  // 1. fused prep: convert x, transpose+convert weights, rpe cumsum
  prep<<<8208, 256, 0, stream>>>(x, xb, qkv, qkvT, out_w, outwT, rpe, cum);
  // 2. QKV projection (V written pre-transposed; 768 blocks = 3/CU, no tail)
  gemm_bt<0><<<dim3(3072 / 128, 4096 / 128), 256, 0, stream>>>(xb, qkvT, qb, kb, vtb, nullptr);
  // 3. attention (R13 structure: K staged via LDS, b32 bias gather)
  fa_kernel<<<1024, 256, 0, stream>>>(qb, kb, vtb, cum, mixb);
  // 4. output projection (f32 out; 128x64 tiles -> 512 blocks = 2/CU)
  gemm_bt<1><<<dim3(1024 / 64, 4096 / 128), 256, 0, stream>>>(mixb, outwT, nullptr, nullptr, nullptr, out);
}